// Round 1
// baseline (302.347 us; speedup 1.0000x reference)
//
#include <hip/hip_runtime.h>
#include <stdint.h>

#define QPF  127.0f
#define MINR 1e-6f

typedef int v4i __attribute__((ext_vector_type(4)));

// ---------- helpers ----------
__device__ __forceinline__ float wave_max64(float v) {
  v = fmaxf(v, __shfl_xor(v, 32, 64));
  v = fmaxf(v, __shfl_xor(v, 16, 64));
  v = fmaxf(v, __shfl_xor(v, 8, 64));
  v = fmaxf(v, __shfl_xor(v, 4, 64));
  v = fmaxf(v, __shfl_xor(v, 2, 64));
  v = fmaxf(v, __shfl_xor(v, 1, 64));
  return v;
}

__device__ __forceinline__ float gelu_exact(float v) {
  return 0.5f * v * (1.0f + erff(v * 0.70710678118654752440f));
}

// async global->LDS, 16B per lane; LDS dest is wave-uniform base + lane*16
__device__ __forceinline__ void gl2lds16(const void* g, void* l) {
  __builtin_amdgcn_global_load_lds(
      (const __attribute__((address_space(1))) int*)g,
      (__attribute__((address_space(3))) int*)l,
      16, 0, 0);
}

// ---------- per-tensor amax ----------
__global__ __launch_bounds__(256) void amax_kernel(const float* __restrict__ w,
                                                   int n4, unsigned* out) {
  const float4* w4 = (const float4*)w;
  float m = 0.f;
  for (int i = blockIdx.x * blockDim.x + threadIdx.x; i < n4;
       i += gridDim.x * blockDim.x) {
    float4 v = w4[i];
    m = fmaxf(m, fmaxf(fmaxf(fabsf(v.x), fabsf(v.y)),
                       fmaxf(fabsf(v.z), fabsf(v.w))));
  }
  m = wave_max64(m);
  __shared__ float red[4];
  const int lane = threadIdx.x & 63, wv = threadIdx.x >> 6;
  if (lane == 0) red[wv] = m;
  __syncthreads();
  if (threadIdx.x == 0) {
    float mm = fmaxf(fmaxf(red[0], red[1]), fmaxf(red[2], red[3]));
    atomicMax(out, __float_as_uint(mm));  // non-negative floats: uint order == float order
  }
}

// ---------- per-tensor weight quantize ----------
__global__ __launch_bounds__(256) void wquant_kernel(const float* __restrict__ w,
                                                     int n4,
                                                     const unsigned* __restrict__ amaxbits,
                                                     signed char* __restrict__ q) {
  const float s = fmaxf(__uint_as_float(*amaxbits), MINR) / QPF;
  const float4* w4 = (const float4*)w;
  char4* q4 = (char4*)q;
  for (int i = blockIdx.x * blockDim.x + threadIdx.x; i < n4;
       i += gridDim.x * blockDim.x) {
    float4 v = w4[i];
    char4 c;
    c.x = (signed char)(int)rintf(v.x / s);
    c.y = (signed char)(int)rintf(v.y / s);
    c.z = (signed char)(int)rintf(v.z / s);
    c.w = (signed char)(int)rintf(v.w / s);
    q4[i] = c;
  }
}

// ---------- per-token activation quantize (one block per token) ----------
__global__ __launch_bounds__(256) void xquant_kernel(const float* __restrict__ x,
                                                     signed char* __restrict__ qx,
                                                     float* __restrict__ sx, int K) {
  const int token = blockIdx.x;
  const float* xr = x + (size_t)token * K;
  float m = 0.f;
  for (int i = threadIdx.x; i < K; i += 256) m = fmaxf(m, fabsf(xr[i]));
  m = wave_max64(m);
  __shared__ float red[4];
  const int lane = threadIdx.x & 63, wv = threadIdx.x >> 6;
  if (lane == 0) red[wv] = m;
  __syncthreads();
  const float M = fmaxf(fmaxf(red[0], red[1]), fmaxf(red[2], red[3]));
  const float s = fmaxf(M, MINR) / QPF;
  if (threadIdx.x == 0) sx[token] = s;
  signed char* qr = qx + (size_t)token * K;
  for (int i = threadIdx.x; i < K; i += 256)
    qr[i] = (signed char)(int)rintf(xr[i] / s);
}

// ---------- per-token h quantize (amax already computed by gemm1 epilogue) ----------
__global__ __launch_bounds__(256) void hquant_kernel(const float* __restrict__ h,
                                                     const unsigned* __restrict__ amaxbits,
                                                     signed char* __restrict__ qh,
                                                     float* __restrict__ sh, int K) {
  const int token = blockIdx.x;
  const float s = fmaxf(__uint_as_float(amaxbits[token]), MINR) / QPF;
  if (threadIdx.x == 0) sh[token] = s;
  const float4* hr = (const float4*)(h + (size_t)token * K);
  char4* qr = (char4*)(qh + (size_t)token * K);
  for (int i = threadIdx.x; i < (K >> 2); i += 256) {
    float4 v = hr[i];
    char4 c;
    c.x = (signed char)(int)rintf(v.x / s);
    c.y = (signed char)(int)rintf(v.y / s);
    c.z = (signed char)(int)rintf(v.z / s);
    c.w = (signed char)(int)rintf(v.w / s);
    qr[i] = c;
  }
}

// ---------- i8 GEMM: out[n][m] = (sum_k A[n][k]*B[m][k] + bias[m]) * (sA[n]*sB) ----------
// 128x128 tile, BK=64, 4 waves in 2x2, each wave 64x64 via 4x4 mfma_i32_16x16x64_i8
template <bool GELU_EPI>
__global__ __launch_bounds__(256, 2) void gemm_i8(
    const signed char* __restrict__ A,   // [N][K]
    const signed char* __restrict__ B,   // [Mout][K]
    const float* __restrict__ bias,      // [Mout]
    const float* __restrict__ sA,        // [N] per-token scale
    const unsigned* __restrict__ sBbits, // per-tensor amax (float bits)
    float* __restrict__ out,             // [N][Mout]
    unsigned* __restrict__ amax_out,     // [N] per-token amax of gelu(out) (GELU path)
    int N, int K, int Mout) {
  __shared__ __align__(16) signed char As[128 * 64];
  __shared__ __align__(16) signed char Bs[128 * 64];

  const int t = threadIdx.x;
  const int lane = t & 63;
  const int wv = t >> 6;       // wave 0..3
  const int wm = wv >> 1;      // wave row half
  const int wn = wv & 1;       // wave col half
  const int rowBlk = blockIdx.y * 128;
  const int colBlk = blockIdx.x * 128;

  // staging: issue i covers rows [i*64 + wv*16 + lane/4], 16B chunk (lane&3)*16
  int ar0 = rowBlk + wv * 16 + (lane >> 2);
  int ar1 = ar0 + 64;
  if (ar0 > N - 1) ar0 = N - 1;   // clamp tail rows (results discarded)
  if (ar1 > N - 1) ar1 = N - 1;
  const int br0 = colBlk + wv * 16 + (lane >> 2);
  const int br1 = br0 + 64;
  const int kb = (lane & 3) * 16;

  const signed char* gA0 = A + (size_t)ar0 * K + kb;
  const signed char* gA1 = A + (size_t)ar1 * K + kb;
  const signed char* gB0 = B + (size_t)br0 * K + kb;
  const signed char* gB1 = B + (size_t)br1 * K + kb;

  signed char* lA0 = As + wv * 1024;
  signed char* lA1 = As + 4096 + wv * 1024;
  signed char* lB0 = Bs + wv * 1024;
  signed char* lB1 = Bs + 4096 + wv * 1024;

  const v4i vzero = {0, 0, 0, 0};
  v4i acc[4][4];
#pragma unroll
  for (int i = 0; i < 4; i++)
#pragma unroll
    for (int j = 0; j < 4; j++) acc[i][j] = vzero;

  // LDS fragment addresses: row m = lane&15 (+16*mi), k chunk = (lane>>4)*16
  const int aoff = (wm * 64 + (lane & 15)) * 64 + (lane >> 4) * 16;
  const int boff = (wn * 64 + (lane & 15)) * 64 + (lane >> 4) * 16;

  for (int kt = 0; kt < K; kt += 64) {
    gl2lds16(gA0, lA0);
    gl2lds16(gA1, lA1);
    gl2lds16(gB0, lB0);
    gl2lds16(gB1, lB1);
    __syncthreads();   // drains vmcnt (global_load_lds) before use

    v4i a[4], b[4];
#pragma unroll
    for (int mi = 0; mi < 4; mi++) a[mi] = *(const v4i*)(As + aoff + mi * 1024);
#pragma unroll
    for (int ni = 0; ni < 4; ni++) b[ni] = *(const v4i*)(Bs + boff + ni * 1024);
#pragma unroll
    for (int mi = 0; mi < 4; mi++)
#pragma unroll
      for (int ni = 0; ni < 4; ni++)
        acc[mi][ni] = __builtin_amdgcn_mfma_i32_16x16x64_i8(a[mi], b[ni],
                                                            acc[mi][ni], 0, 0, 0);
    __syncthreads();   // LDS reuse barrier
    gA0 += 64; gA1 += 64; gB0 += 64; gB1 += 64;
  }

  // epilogue: C/D layout col=lane&15, row=(lane>>4)*4+r (dtype-independent)
  const float sB = fmaxf(__uint_as_float(*sBbits), MINR) / QPF;
  const int colb = colBlk + wn * 64 + (lane & 15);
  const int rowb = rowBlk + wm * 64 + (lane >> 4) * 4;

  float bv[4];
#pragma unroll
  for (int ni = 0; ni < 4; ni++) bv[ni] = bias[colb + ni * 16];

#pragma unroll
  for (int mi = 0; mi < 4; mi++) {
    const int row0 = rowb + mi * 16;
    float sAv[4];
#pragma unroll
    for (int r = 0; r < 4; r++) sAv[r] = (row0 + r < N) ? sA[row0 + r] : 0.f;
    float rmax[4] = {0.f, 0.f, 0.f, 0.f};
#pragma unroll
    for (int ni = 0; ni < 4; ni++) {
#pragma unroll
      for (int r = 0; r < 4; r++) {
        float v = ((float)acc[mi][ni][r] + bv[ni]) * (sAv[r] * sB);
        if (GELU_EPI) v = gelu_exact(v);
        rmax[r] = fmaxf(rmax[r], fabsf(v));
        if (row0 + r < N)
          out[(size_t)(row0 + r) * Mout + colb + ni * 16] = v;
      }
    }
    if (GELU_EPI) {
      // per-row amax over this block's 128 cols: reduce across lane&15 group
#pragma unroll
      for (int r = 0; r < 4; r++) {
        float m = rmax[r];
        m = fmaxf(m, __shfl_xor(m, 1, 64));
        m = fmaxf(m, __shfl_xor(m, 2, 64));
        m = fmaxf(m, __shfl_xor(m, 4, 64));
        m = fmaxf(m, __shfl_xor(m, 8, 64));
        if ((lane & 15) == 0 && row0 + r < N)
          atomicMax(amax_out + row0 + r, __float_as_uint(m));
      }
    }
  }
}

extern "C" void kernel_launch(void* const* d_in, const int* in_sizes, int n_in,
                              void* d_out, int out_size, void* d_ws, size_t ws_size,
                              hipStream_t stream) {
  const float* x  = (const float*)d_in[0];
  const float* w1 = (const float*)d_in[1];
  const float* b1 = (const float*)d_in[2];
  const float* w2 = (const float*)d_in[3];
  const float* b2 = (const float*)d_in[4];

  const int H = in_sizes[2];        // 3072
  const int D = in_sizes[4];        // 768
  const int N = in_sizes[0] / D;    // 12608 tokens
  float* out = (float*)d_out;

  // workspace carve-up (~208 MB)
  char* ws = (char*)d_ws;
  auto alloc = [&](size_t bytes) {
    char* p = ws;
    ws += (bytes + 255) & ~(size_t)255;
    return p;
  };
  signed char* qx  = (signed char*)alloc((size_t)N * D);
  signed char* qw1 = (signed char*)alloc((size_t)H * D);
  signed char* qw2 = (signed char*)alloc((size_t)H * D);
  signed char* qh  = (signed char*)alloc((size_t)N * H);
  float*    sx     = (float*)alloc((size_t)N * 4);
  float*    sh     = (float*)alloc((size_t)N * 4);
  unsigned* amaxh  = (unsigned*)alloc((size_t)N * 4);
  unsigned* wamax  = (unsigned*)alloc(256);
  float*    h      = (float*)alloc((size_t)N * H * 4);
  (void)ws_size;

  // zero the atomic-max accumulators (ws is poisoned 0xAA before every call)
  hipMemsetAsync(amaxh, 0, (size_t)N * 4, stream);
  hipMemsetAsync(wamax, 0, 8, stream);

  const int n4w = (H * D) >> 2;
  amax_kernel<<<512, 256, 0, stream>>>(w1, n4w, wamax + 0);
  amax_kernel<<<512, 256, 0, stream>>>(w2, n4w, wamax + 1);
  wquant_kernel<<<1024, 256, 0, stream>>>(w1, n4w, wamax + 0, qw1);
  wquant_kernel<<<1024, 256, 0, stream>>>(w2, n4w, wamax + 1, qw2);
  xquant_kernel<<<N, 256, 0, stream>>>(x, qx, sx, D);

  dim3 g1(H / 128, (N + 127) / 128);
  gemm_i8<true><<<g1, 256, 0, stream>>>(qx, qw1, b1, sx, wamax + 0, h, amaxh,
                                        N, D, H);
  hquant_kernel<<<N, 256, 0, stream>>>(h, amaxh, qh, sh, H);

  dim3 g2(D / 128, (N + 127) / 128);
  gemm_i8<false><<<g2, 256, 0, stream>>>(qh, qw2, b2, sh, wamax + 1, out,
                                         nullptr, N, H, D);
}

// Round 2
// 284.142 us; speedup vs baseline: 1.0641x; 1.0641x over previous
//
#include <hip/hip_runtime.h>
#include <stdint.h>

#define QPF  127.0f
#define MINR 1e-6f

typedef int v4i __attribute__((ext_vector_type(4)));

// ---------- helpers ----------
__device__ __forceinline__ float wave_max64(float v) {
  v = fmaxf(v, __shfl_xor(v, 32, 64));
  v = fmaxf(v, __shfl_xor(v, 16, 64));
  v = fmaxf(v, __shfl_xor(v, 8, 64));
  v = fmaxf(v, __shfl_xor(v, 4, 64));
  v = fmaxf(v, __shfl_xor(v, 2, 64));
  v = fmaxf(v, __shfl_xor(v, 1, 64));
  return v;
}

// Exact-GELU via Abramowitz-Stegun 7.1.26 erf (|eps| <= 1.5e-7), branchless.
// ~15 VALU + v_exp_f32, vs ocml erff's branchy ~50 ops.
__device__ __forceinline__ float gelu_exact(float x) {
  float z = fabsf(x) * 0.70710678118654752440f;
  float t = __builtin_amdgcn_rcpf(fmaf(0.3275911f, z, 1.0f));
  float p = fmaf(fmaf(fmaf(fmaf(1.061405429f, t, -1.453152027f), t,
                           1.421413741f), t, -0.284496736f), t, 0.254829592f) * t;
  float e = __expf(-z * z);
  float erfz = fmaf(-p, e, 1.0f);            // erf(|z|), >= 0
  float cdf = fmaf(0.5f, copysignf(erfz, x), 0.5f);
  return x * cdf;
}

// async global->LDS, 16B per lane; LDS dest is wave-uniform base + lane*16
__device__ __forceinline__ void gl2lds16(const void* g, void* l) {
  __builtin_amdgcn_global_load_lds(
      (const __attribute__((address_space(1))) int*)g,
      (__attribute__((address_space(3))) int*)l,
      16, 0, 0);
}

// ---------- per-tensor amax ----------
__global__ __launch_bounds__(256) void amax_kernel(const float* __restrict__ w,
                                                   int n4, unsigned* out) {
  const float4* w4 = (const float4*)w;
  float m = 0.f;
  for (int i = blockIdx.x * blockDim.x + threadIdx.x; i < n4;
       i += gridDim.x * blockDim.x) {
    float4 v = w4[i];
    m = fmaxf(m, fmaxf(fmaxf(fabsf(v.x), fabsf(v.y)),
                       fmaxf(fabsf(v.z), fabsf(v.w))));
  }
  m = wave_max64(m);
  __shared__ float red[4];
  const int lane = threadIdx.x & 63, wv = threadIdx.x >> 6;
  if (lane == 0) red[wv] = m;
  __syncthreads();
  if (threadIdx.x == 0) {
    float mm = fmaxf(fmaxf(red[0], red[1]), fmaxf(red[2], red[3]));
    atomicMax(out, __float_as_uint(mm));  // non-negative floats: uint order == float order
  }
}

// ---------- per-tensor weight quantize ----------
__global__ __launch_bounds__(256) void wquant_kernel(const float* __restrict__ w,
                                                     int n4,
                                                     const unsigned* __restrict__ amaxbits,
                                                     signed char* __restrict__ q) {
  const float s = fmaxf(__uint_as_float(*amaxbits), MINR) / QPF;
  const float rs = 1.0f / s;
  const float4* w4 = (const float4*)w;
  char4* q4 = (char4*)q;
  for (int i = blockIdx.x * blockDim.x + threadIdx.x; i < n4;
       i += gridDim.x * blockDim.x) {
    float4 v = w4[i];
    char4 c;
    c.x = (signed char)(int)rintf(v.x * rs);
    c.y = (signed char)(int)rintf(v.y * rs);
    c.z = (signed char)(int)rintf(v.z * rs);
    c.w = (signed char)(int)rintf(v.w * rs);
    q4[i] = c;
  }
}

// ---------- per-token activation quantize (one block per token) ----------
__global__ __launch_bounds__(256) void xquant_kernel(const float* __restrict__ x,
                                                     signed char* __restrict__ qx,
                                                     float* __restrict__ sx, int K) {
  const int token = blockIdx.x;
  const float4* xr = (const float4*)(x + (size_t)token * K);
  const int k4 = K >> 2;
  float m = 0.f;
  for (int i = threadIdx.x; i < k4; i += 256) {
    float4 v = xr[i];
    m = fmaxf(m, fmaxf(fmaxf(fabsf(v.x), fabsf(v.y)),
                       fmaxf(fabsf(v.z), fabsf(v.w))));
  }
  m = wave_max64(m);
  __shared__ float red[4];
  const int lane = threadIdx.x & 63, wv = threadIdx.x >> 6;
  if (lane == 0) red[wv] = m;
  __syncthreads();
  const float M = fmaxf(fmaxf(red[0], red[1]), fmaxf(red[2], red[3]));
  const float s = fmaxf(M, MINR) / QPF;
  const float rs = 1.0f / s;
  if (threadIdx.x == 0) sx[token] = s;
  char4* qr = (char4*)(qx + (size_t)token * K);
  for (int i = threadIdx.x; i < k4; i += 256) {
    float4 v = xr[i];
    char4 c;
    c.x = (signed char)(int)rintf(v.x * rs);
    c.y = (signed char)(int)rintf(v.y * rs);
    c.z = (signed char)(int)rintf(v.z * rs);
    c.w = (signed char)(int)rintf(v.w * rs);
    qr[i] = c;
  }
}

// ---------- per-token h quantize (amax computed by gemm1 epilogue) ----------
__global__ __launch_bounds__(256) void hquant_kernel(const float* __restrict__ h,
                                                     const unsigned* __restrict__ amaxbits,
                                                     signed char* __restrict__ qh,
                                                     float* __restrict__ sh, int K) {
  const int token = blockIdx.x;
  const float s = fmaxf(__uint_as_float(amaxbits[token]), MINR) / QPF;
  const float rs = 1.0f / s;
  if (threadIdx.x == 0) sh[token] = s;
  const float4* hr = (const float4*)(h + (size_t)token * K);
  char4* qr = (char4*)(qh + (size_t)token * K);
  for (int i = threadIdx.x; i < (K >> 2); i += 256) {
    float4 v = hr[i];
    char4 c;
    c.x = (signed char)(int)rintf(v.x * rs);
    c.y = (signed char)(int)rintf(v.y * rs);
    c.z = (signed char)(int)rintf(v.z * rs);
    c.w = (signed char)(int)rintf(v.w * rs);
    qr[i] = c;
  }
}

// ---------- i8 GEMM: out[n][m] = (sum_k A[n][k]*B[m][k] + bias[m]) * (sA[n]*sB) ----------
// 128x128 tile, BK=64, 4 waves in 2x2, each wave 64x64 via 4x4 mfma_i32_16x16x64_i8.
// LDS rows are 64B; 16B chunks XOR-swizzled by ((row>>1)&3) so the fragment
// ds_read_b128 spreads 16 rows over 8 bank-groups (2 lanes/bank = conflict-free).
template <bool GELU_EPI>
__global__ __launch_bounds__(256, 2) void gemm_i8(
    const signed char* __restrict__ A,   // [N][K]
    const signed char* __restrict__ B,   // [Mout][K]
    const float* __restrict__ bias,      // [Mout]
    const float* __restrict__ sA,        // [N] per-token scale
    const unsigned* __restrict__ sBbits, // per-tensor amax (float bits)
    float* __restrict__ out,             // [N][Mout]
    unsigned* __restrict__ amax_out,     // [N] per-token amax of gelu(out) (GELU path)
    int N, int K, int Mout) {
  __shared__ __align__(16) signed char As[128 * 64];
  __shared__ __align__(16) signed char Bs[128 * 64];

  const int t = threadIdx.x;
  const int lane = t & 63;
  const int wv = t >> 6;       // wave 0..3
  const int wm = wv >> 1;      // wave row half
  const int wn = wv & 1;       // wave col half
  const int rowBlk = blockIdx.y * 128;
  const int colBlk = blockIdx.x * 128;

  // staging: each gl2lds16 issue covers 16 rows x 64B contiguous in LDS.
  // lane -> (row = lane>>2, chunk' = lane&3); global chunk = chunk' ^ ((lane>>3)&3)
  int ar0 = rowBlk + wv * 16 + (lane >> 2);
  int ar1 = ar0 + 64;
  if (ar0 > N - 1) ar0 = N - 1;   // clamp tail rows (results discarded)
  if (ar1 > N - 1) ar1 = N - 1;
  const int br0 = colBlk + wv * 16 + (lane >> 2);
  const int br1 = br0 + 64;
  const int kb = (((lane & 3) ^ ((lane >> 3) & 3)) * 16);  // swizzled source chunk

  const signed char* gA0 = A + (size_t)ar0 * K + kb;
  const signed char* gA1 = A + (size_t)ar1 * K + kb;
  const signed char* gB0 = B + (size_t)br0 * K + kb;
  const signed char* gB1 = B + (size_t)br1 * K + kb;

  signed char* lA0 = As + wv * 1024;
  signed char* lA1 = As + 4096 + wv * 1024;
  signed char* lB0 = Bs + wv * 1024;
  signed char* lB1 = Bs + 4096 + wv * 1024;

  const v4i vzero = {0, 0, 0, 0};
  v4i acc[4][4];
#pragma unroll
  for (int i = 0; i < 4; i++)
#pragma unroll
    for (int j = 0; j < 4; j++) acc[i][j] = vzero;

  // fragment read: row m = lane&15 (+16*mi), chunk c = lane>>4, un-swizzle with
  // ((row>>1)&3) — invariant under mi*16 row steps, so +mi*1024 still works.
  const int swz = ((lane >> 4) ^ ((lane >> 1) & 3)) * 16;
  const int aoff = (wm * 64 + (lane & 15)) * 64 + swz;
  const int boff = (wn * 64 + (lane & 15)) * 64 + swz;

  for (int kt = 0; kt < K; kt += 64) {
    gl2lds16(gA0, lA0);
    gl2lds16(gA1, lA1);
    gl2lds16(gB0, lB0);
    gl2lds16(gB1, lB1);
    __syncthreads();   // drains vmcnt (global_load_lds) before use

    v4i a[4], b[4];
#pragma unroll
    for (int mi = 0; mi < 4; mi++) a[mi] = *(const v4i*)(As + aoff + mi * 1024);
#pragma unroll
    for (int ni = 0; ni < 4; ni++) b[ni] = *(const v4i*)(Bs + boff + ni * 1024);
#pragma unroll
    for (int mi = 0; mi < 4; mi++)
#pragma unroll
      for (int ni = 0; ni < 4; ni++)
        acc[mi][ni] = __builtin_amdgcn_mfma_i32_16x16x64_i8(a[mi], b[ni],
                                                            acc[mi][ni], 0, 0, 0);
    __syncthreads();   // LDS reuse barrier
    gA0 += 64; gA1 += 64; gB0 += 64; gB1 += 64;
  }

  // epilogue: C/D layout col=lane&15, row=(lane>>4)*4+r (dtype-independent)
  const float sB = fmaxf(__uint_as_float(*sBbits), MINR) / QPF;
  const int colb = colBlk + wn * 64 + (lane & 15);
  const int rowb = rowBlk + wm * 64 + (lane >> 4) * 4;

  float bv[4];
#pragma unroll
  for (int ni = 0; ni < 4; ni++) bv[ni] = bias[colb + ni * 16];

#pragma unroll
  for (int mi = 0; mi < 4; mi++) {
    const int row0 = rowb + mi * 16;
    float sAv[4];
#pragma unroll
    for (int r = 0; r < 4; r++) sAv[r] = (row0 + r < N) ? sA[row0 + r] : 0.f;
    float rmax[4] = {0.f, 0.f, 0.f, 0.f};
#pragma unroll
    for (int ni = 0; ni < 4; ni++) {
#pragma unroll
      for (int r = 0; r < 4; r++) {
        float v = ((float)acc[mi][ni][r] + bv[ni]) * (sAv[r] * sB);
        if (GELU_EPI) v = gelu_exact(v);
        rmax[r] = fmaxf(rmax[r], fabsf(v));
        if (row0 + r < N)
          out[(size_t)(row0 + r) * Mout + colb + ni * 16] = v;
      }
    }
    if (GELU_EPI) {
      // per-row amax over this block's 128 cols: reduce across lane&15 group
#pragma unroll
      for (int r = 0; r < 4; r++) {
        float m = rmax[r];
        m = fmaxf(m, __shfl_xor(m, 1, 64));
        m = fmaxf(m, __shfl_xor(m, 2, 64));
        m = fmaxf(m, __shfl_xor(m, 4, 64));
        m = fmaxf(m, __shfl_xor(m, 8, 64));
        if ((lane & 15) == 0 && row0 + r < N)
          atomicMax(amax_out + row0 + r, __float_as_uint(m));
      }
    }
  }
}

extern "C" void kernel_launch(void* const* d_in, const int* in_sizes, int n_in,
                              void* d_out, int out_size, void* d_ws, size_t ws_size,
                              hipStream_t stream) {
  const float* x  = (const float*)d_in[0];
  const float* w1 = (const float*)d_in[1];
  const float* b1 = (const float*)d_in[2];
  const float* w2 = (const float*)d_in[3];
  const float* b2 = (const float*)d_in[4];

  const int H = in_sizes[2];        // 3072
  const int D = in_sizes[4];        // 768
  const int N = in_sizes[0] / D;    // 12608 tokens
  float* out = (float*)d_out;

  // workspace carve-up (~208 MB)
  char* ws = (char*)d_ws;
  auto alloc = [&](size_t bytes) {
    char* p = ws;
    ws += (bytes + 255) & ~(size_t)255;
    return p;
  };
  signed char* qx  = (signed char*)alloc((size_t)N * D);
  signed char* qw1 = (signed char*)alloc((size_t)H * D);
  signed char* qw2 = (signed char*)alloc((size_t)H * D);
  signed char* qh  = (signed char*)alloc((size_t)N * H);
  float*    sx     = (float*)alloc((size_t)N * 4);
  float*    sh     = (float*)alloc((size_t)N * 4);
  unsigned* amaxh  = (unsigned*)alloc((size_t)N * 4);
  unsigned* wamax  = (unsigned*)alloc(256);
  float*    h      = (float*)alloc((size_t)N * H * 4);
  (void)ws_size;

  // zero the atomic-max accumulators (ws is poisoned 0xAA before every call)
  hipMemsetAsync(amaxh, 0, (size_t)N * 4, stream);
  hipMemsetAsync(wamax, 0, 8, stream);

  const int n4w = (H * D) >> 2;
  amax_kernel<<<512, 256, 0, stream>>>(w1, n4w, wamax + 0);
  amax_kernel<<<512, 256, 0, stream>>>(w2, n4w, wamax + 1);
  wquant_kernel<<<1024, 256, 0, stream>>>(w1, n4w, wamax + 0, qw1);
  wquant_kernel<<<1024, 256, 0, stream>>>(w2, n4w, wamax + 1, qw2);
  xquant_kernel<<<N, 256, 0, stream>>>(x, qx, sx, D);

  dim3 g1(H / 128, (N + 127) / 128);
  gemm_i8<true><<<g1, 256, 0, stream>>>(qx, qw1, b1, sx, wamax + 0, h, amaxh,
                                        N, D, H);
  hquant_kernel<<<N, 256, 0, stream>>>(h, amaxh, qh, sh, H);

  dim3 g2(D / 128, (N + 127) / 128);
  gemm_i8<false><<<g2, 256, 0, stream>>>(qh, qw2, b2, sh, wamax + 1, out,
                                         nullptr, N, H, D);
}

// Round 3
// 272.346 us; speedup vs baseline: 1.1102x; 1.0433x over previous
//
#include <hip/hip_runtime.h>
#include <stdint.h>

#define QPF  127.0f
#define MINR 1e-6f

typedef int v4i __attribute__((ext_vector_type(4)));
typedef _Float16 h8 __attribute__((ext_vector_type(8)));
typedef signed char c8 __attribute__((ext_vector_type(8)));

// ---------- helpers ----------
__device__ __forceinline__ float wave_max64(float v) {
  v = fmaxf(v, __shfl_xor(v, 32, 64));
  v = fmaxf(v, __shfl_xor(v, 16, 64));
  v = fmaxf(v, __shfl_xor(v, 8, 64));
  v = fmaxf(v, __shfl_xor(v, 4, 64));
  v = fmaxf(v, __shfl_xor(v, 2, 64));
  v = fmaxf(v, __shfl_xor(v, 1, 64));
  return v;
}

// Exact-GELU via A&S 7.1.26 erf (|eps| <= 1.5e-7), branchless.
__device__ __forceinline__ float gelu_exact(float x) {
  float z = fabsf(x) * 0.70710678118654752440f;
  float t = __builtin_amdgcn_rcpf(fmaf(0.3275911f, z, 1.0f));
  float p = fmaf(fmaf(fmaf(fmaf(1.061405429f, t, -1.453152027f), t,
                           1.421413741f), t, -0.284496736f), t, 0.254829592f) * t;
  float e = __expf(-z * z);
  float erfz = fmaf(-p, e, 1.0f);
  float cdf = fmaf(0.5f, copysignf(erfz, x), 0.5f);
  return x * cdf;
}

// async global->LDS, 16B per lane; LDS dest is wave-uniform base + lane*16
__device__ __forceinline__ void gl2lds16(const void* g, void* l) {
  __builtin_amdgcn_global_load_lds(
      (const __attribute__((address_space(1))) int*)g,
      (__attribute__((address_space(3))) int*)l,
      16, 0, 0);
}

// ---------- per-tensor amax ----------
__global__ __launch_bounds__(256) void amax_kernel(const float* __restrict__ w,
                                                   int n4, unsigned* out) {
  const float4* w4 = (const float4*)w;
  float m = 0.f;
  for (int i = blockIdx.x * blockDim.x + threadIdx.x; i < n4;
       i += gridDim.x * blockDim.x) {
    float4 v = w4[i];
    m = fmaxf(m, fmaxf(fmaxf(fabsf(v.x), fabsf(v.y)),
                       fmaxf(fabsf(v.z), fabsf(v.w))));
  }
  m = wave_max64(m);
  __shared__ float red[4];
  const int lane = threadIdx.x & 63, wv = threadIdx.x >> 6;
  if (lane == 0) red[wv] = m;
  __syncthreads();
  if (threadIdx.x == 0) {
    float mm = fmaxf(fmaxf(red[0], red[1]), fmaxf(red[2], red[3]));
    atomicMax(out, __float_as_uint(mm));
  }
}

// ---------- per-tensor weight quantize ----------
__global__ __launch_bounds__(256) void wquant_kernel(const float* __restrict__ w,
                                                     int n4,
                                                     const unsigned* __restrict__ amaxbits,
                                                     signed char* __restrict__ q) {
  const float s = fmaxf(__uint_as_float(*amaxbits), MINR) / QPF;
  const float rs = 1.0f / s;
  const float4* w4 = (const float4*)w;
  char4* q4 = (char4*)q;
  for (int i = blockIdx.x * blockDim.x + threadIdx.x; i < n4;
       i += gridDim.x * blockDim.x) {
    float4 v = w4[i];
    char4 c;
    c.x = (signed char)(int)rintf(v.x * rs);
    c.y = (signed char)(int)rintf(v.y * rs);
    c.z = (signed char)(int)rintf(v.z * rs);
    c.w = (signed char)(int)rintf(v.w * rs);
    q4[i] = c;
  }
}

// ---------- per-token activation quantize (one block per token) ----------
__global__ __launch_bounds__(256) void xquant_kernel(const float* __restrict__ x,
                                                     signed char* __restrict__ qx,
                                                     float* __restrict__ sx, int K) {
  const int token = blockIdx.x;
  const float4* xr = (const float4*)(x + (size_t)token * K);
  const int k4 = K >> 2;
  float m = 0.f;
  for (int i = threadIdx.x; i < k4; i += 256) {
    float4 v = xr[i];
    m = fmaxf(m, fmaxf(fmaxf(fabsf(v.x), fabsf(v.y)),
                       fmaxf(fabsf(v.z), fabsf(v.w))));
  }
  m = wave_max64(m);
  __shared__ float red[4];
  const int lane = threadIdx.x & 63, wv = threadIdx.x >> 6;
  if (lane == 0) red[wv] = m;
  __syncthreads();
  const float M = fmaxf(fmaxf(red[0], red[1]), fmaxf(red[2], red[3]));
  const float s = fmaxf(M, MINR) / QPF;
  const float rs = 1.0f / s;
  if (threadIdx.x == 0) sx[token] = s;
  char4* qr = (char4*)(qx + (size_t)token * K);
  for (int i = threadIdx.x; i < k4; i += 256) {
    float4 v = xr[i];
    char4 c;
    c.x = (signed char)(int)rintf(v.x * rs);
    c.y = (signed char)(int)rintf(v.y * rs);
    c.z = (signed char)(int)rintf(v.z * rs);
    c.w = (signed char)(int)rintf(v.w * rs);
    qr[i] = c;
  }
}

// ---------- per-token h quantize (f16 h; amax computed by gemm1 epilogue) ----------
__global__ __launch_bounds__(256) void hquant_kernel(const _Float16* __restrict__ h,
                                                     const unsigned* __restrict__ amaxbits,
                                                     signed char* __restrict__ qh,
                                                     float* __restrict__ sh, int K) {
  const int token = blockIdx.x;
  const float s = fmaxf(__uint_as_float(amaxbits[token]), MINR) / QPF;
  const float rs = 1.0f / s;
  if (threadIdx.x == 0) sh[token] = s;
  const h8* hr = (const h8*)(h + (size_t)token * K);
  c8* qr = (c8*)(qh + (size_t)token * K);
  for (int i = threadIdx.x; i < (K >> 3); i += 256) {
    h8 v = hr[i];
    c8 c;
#pragma unroll
    for (int j = 0; j < 8; j++)
      c[j] = (signed char)(int)rintf((float)v[j] * rs);
    qr[i] = c;
  }
}

// ---------- i8 GEMM: out[n][m] = (sum_k A[n][k]*B[m][k] + bias[m]) * (sA[n]*sB) ----------
// 128x128 tile, BK=64, 4 waves in 2x2, each wave 64x64 via 4x4 mfma_i32_16x16x64_i8.
// XOR-swizzled LDS (conflict-free, verified R2). Double-buffered 1-barrier K-loop:
// tile t+1 loads issued before compute(t), so the next barrier's vmcnt(0) drain
// lands after ~1 tile of compute instead of exposing full load latency.
template <bool GELU_EPI>
__global__ __launch_bounds__(256, 2) void gemm_i8(
    const signed char* __restrict__ A,   // [N][K]
    const signed char* __restrict__ B,   // [Mout][K]
    const float* __restrict__ bias,      // [Mout]
    const float* __restrict__ sA,        // [N] per-token scale
    const unsigned* __restrict__ sBbits, // per-tensor amax (float bits)
    void* __restrict__ outv,             // [N][Mout] (f16 if GELU_EPI else f32)
    unsigned* __restrict__ amax_out,     // [N] per-token amax of gelu(out)
    int N, int K, int Mout) {
  __shared__ __align__(16) signed char As[2 * 128 * 64];
  __shared__ __align__(16) signed char Bs[2 * 128 * 64];

  const int t = threadIdx.x;
  const int lane = t & 63;
  const int wv = t >> 6;
  const int wm = wv >> 1;
  const int wn = wv & 1;
  const int rowBlk = blockIdx.y * 128;
  const int colBlk = blockIdx.x * 128;

  int ar0 = rowBlk + wv * 16 + (lane >> 2);
  int ar1 = ar0 + 64;
  if (ar0 > N - 1) ar0 = N - 1;
  if (ar1 > N - 1) ar1 = N - 1;
  const int br0 = colBlk + wv * 16 + (lane >> 2);
  const int br1 = br0 + 64;
  const int kb = (((lane & 3) ^ ((lane >> 3) & 3)) * 16);  // swizzled source chunk

  const signed char* gA0 = A + (size_t)ar0 * K + kb;
  const signed char* gA1 = A + (size_t)ar1 * K + kb;
  const signed char* gB0 = B + (size_t)br0 * K + kb;
  const signed char* gB1 = B + (size_t)br1 * K + kb;

  const v4i vzero = {0, 0, 0, 0};
  v4i acc[4][4];
#pragma unroll
  for (int i = 0; i < 4; i++)
#pragma unroll
    for (int j = 0; j < 4; j++) acc[i][j] = vzero;

  const int swz = ((lane >> 4) ^ ((lane >> 1) & 3)) * 16;
  const int aoff = (wm * 64 + (lane & 15)) * 64 + swz;
  const int boff = (wn * 64 + (lane & 15)) * 64 + swz;

  const int T = K >> 6;

  // prologue: stage tile 0 into buffer 0
  {
    signed char* a = As + wv * 1024;
    signed char* b = Bs + wv * 1024;
    gl2lds16(gA0, a);
    gl2lds16(gA1, a + 4096);
    gl2lds16(gB0, b);
    gl2lds16(gB1, b + 4096);
    gA0 += 64; gA1 += 64; gB0 += 64; gB1 += 64;
  }

  int buf = 0;
  for (int kt = 0; kt < T; ++kt) {
    __syncthreads();  // drains vmcnt: tile-kt loads complete; syncs LDS reuse
    if (kt + 1 < T) {
      const int o = (buf ^ 1) * 8192;
      signed char* a = As + o + wv * 1024;
      signed char* b = Bs + o + wv * 1024;
      gl2lds16(gA0, a);
      gl2lds16(gA1, a + 4096);
      gl2lds16(gB0, b);
      gl2lds16(gB1, b + 4096);
      gA0 += 64; gA1 += 64; gB0 += 64; gB1 += 64;
    }
    const int o = buf * 8192;
    v4i a[4], b[4];
#pragma unroll
    for (int mi = 0; mi < 4; mi++) a[mi] = *(const v4i*)(As + o + aoff + mi * 1024);
#pragma unroll
    for (int ni = 0; ni < 4; ni++) b[ni] = *(const v4i*)(Bs + o + boff + ni * 1024);
#pragma unroll
    for (int mi = 0; mi < 4; mi++)
#pragma unroll
      for (int ni = 0; ni < 4; ni++)
        acc[mi][ni] = __builtin_amdgcn_mfma_i32_16x16x64_i8(a[mi], b[ni],
                                                            acc[mi][ni], 0, 0, 0);
    buf ^= 1;
  }

  // epilogue: C/D layout col=lane&15, row=(lane>>4)*4+r
  const float sB = fmaxf(__uint_as_float(*sBbits), MINR) / QPF;
  const int colb = colBlk + wn * 64 + (lane & 15);
  const int rowb = rowBlk + wm * 64 + (lane >> 4) * 4;

  float bv[4];
#pragma unroll
  for (int ni = 0; ni < 4; ni++) bv[ni] = bias[colb + ni * 16];

#pragma unroll
  for (int mi = 0; mi < 4; mi++) {
    const int row0 = rowb + mi * 16;
    float sAv[4];
#pragma unroll
    for (int r = 0; r < 4; r++) sAv[r] = (row0 + r < N) ? sA[row0 + r] : 0.f;
    float rmax[4] = {0.f, 0.f, 0.f, 0.f};
#pragma unroll
    for (int ni = 0; ni < 4; ni++) {
#pragma unroll
      for (int r = 0; r < 4; r++) {
        float v = ((float)acc[mi][ni][r] + bv[ni]) * (sAv[r] * sB);
        if (GELU_EPI) v = gelu_exact(v);
        rmax[r] = fmaxf(rmax[r], fabsf(v));
        if (row0 + r < N) {
          const size_t idx = (size_t)(row0 + r) * Mout + colb + ni * 16;
          if (GELU_EPI)
            ((_Float16*)outv)[idx] = (_Float16)v;
          else
            ((float*)outv)[idx] = v;
        }
      }
    }
    if (GELU_EPI) {
#pragma unroll
      for (int r = 0; r < 4; r++) {
        float m = rmax[r];
        m = fmaxf(m, __shfl_xor(m, 1, 64));
        m = fmaxf(m, __shfl_xor(m, 2, 64));
        m = fmaxf(m, __shfl_xor(m, 4, 64));
        m = fmaxf(m, __shfl_xor(m, 8, 64));
        if ((lane & 15) == 0 && row0 + r < N)
          atomicMax(amax_out + row0 + r, __float_as_uint(m));
      }
    }
  }
}

extern "C" void kernel_launch(void* const* d_in, const int* in_sizes, int n_in,
                              void* d_out, int out_size, void* d_ws, size_t ws_size,
                              hipStream_t stream) {
  const float* x  = (const float*)d_in[0];
  const float* w1 = (const float*)d_in[1];
  const float* b1 = (const float*)d_in[2];
  const float* w2 = (const float*)d_in[3];
  const float* b2 = (const float*)d_in[4];

  const int H = in_sizes[2];        // 3072
  const int D = in_sizes[4];        // 768
  const int N = in_sizes[0] / D;    // 12608 tokens
  float* out = (float*)d_out;

  char* ws = (char*)d_ws;
  auto alloc = [&](size_t bytes) {
    char* p = ws;
    ws += (bytes + 255) & ~(size_t)255;
    return p;
  };
  signed char* qx  = (signed char*)alloc((size_t)N * D);
  signed char* qw1 = (signed char*)alloc((size_t)H * D);
  signed char* qw2 = (signed char*)alloc((size_t)H * D);
  signed char* qh  = (signed char*)alloc((size_t)N * H);
  float*    sx     = (float*)alloc((size_t)N * 4);
  float*    sh     = (float*)alloc((size_t)N * 4);
  unsigned* amaxh  = (unsigned*)alloc((size_t)N * 4);
  unsigned* wamax  = (unsigned*)alloc(256);
  _Float16* h      = (_Float16*)alloc((size_t)N * H * 2);
  (void)ws_size;

  hipMemsetAsync(amaxh, 0, (size_t)N * 4, stream);
  hipMemsetAsync(wamax, 0, 8, stream);

  const int n4w = (H * D) >> 2;
  amax_kernel<<<512, 256, 0, stream>>>(w1, n4w, wamax + 0);
  amax_kernel<<<512, 256, 0, stream>>>(w2, n4w, wamax + 1);
  wquant_kernel<<<1024, 256, 0, stream>>>(w1, n4w, wamax + 0, qw1);
  wquant_kernel<<<1024, 256, 0, stream>>>(w2, n4w, wamax + 1, qw2);
  xquant_kernel<<<N, 256, 0, stream>>>(x, qx, sx, D);

  dim3 g1(H / 128, (N + 127) / 128);
  gemm_i8<true><<<g1, 256, 0, stream>>>(qx, qw1, b1, sx, wamax + 0, (void*)h,
                                        amaxh, N, D, H);
  hquant_kernel<<<N, 256, 0, stream>>>(h, amaxh, qh, sh, H);

  dim3 g2(D / 128, (N + 127) / 128);
  gemm_i8<false><<<g2, 256, 0, stream>>>(qh, qw2, b2, sh, wamax + 1, (void*)out,
                                         nullptr, N, H, D);
}

// Round 4
// 266.283 us; speedup vs baseline: 1.1354x; 1.0228x over previous
//
#include <hip/hip_runtime.h>
#include <stdint.h>

#define QPF  127.0f
#define MINR 1e-6f

typedef int v4i __attribute__((ext_vector_type(4)));
typedef _Float16 h8 __attribute__((ext_vector_type(8)));
typedef signed char c8 __attribute__((ext_vector_type(8)));

// ---------- helpers ----------
__device__ __forceinline__ float wave_max64(float v) {
  v = fmaxf(v, __shfl_xor(v, 32, 64));
  v = fmaxf(v, __shfl_xor(v, 16, 64));
  v = fmaxf(v, __shfl_xor(v, 8, 64));
  v = fmaxf(v, __shfl_xor(v, 4, 64));
  v = fmaxf(v, __shfl_xor(v, 2, 64));
  v = fmaxf(v, __shfl_xor(v, 1, 64));
  return v;
}

// Exact-GELU via A&S 7.1.26 erf (|eps| <= 1.5e-7), branchless.
__device__ __forceinline__ float gelu_exact(float x) {
  float z = fabsf(x) * 0.70710678118654752440f;
  float t = __builtin_amdgcn_rcpf(fmaf(0.3275911f, z, 1.0f));
  float p = fmaf(fmaf(fmaf(fmaf(1.061405429f, t, -1.453152027f), t,
                           1.421413741f), t, -0.284496736f), t, 0.254829592f) * t;
  float e = __expf(-z * z);
  float erfz = fmaf(-p, e, 1.0f);
  float cdf = fmaf(0.5f, copysignf(erfz, x), 0.5f);
  return x * cdf;
}

// async global->LDS, 16B per lane; LDS dest is wave-uniform base + lane*16
__device__ __forceinline__ void gl2lds16(const void* g, void* l) {
  __builtin_amdgcn_global_load_lds(
      (const __attribute__((address_space(1))) int*)g,
      (__attribute__((address_space(3))) int*)l,
      16, 0, 0);
}

// ---------- per-tensor amax (both weight tensors; blockIdx.y selects) ----------
__global__ __launch_bounds__(256) void amax2_kernel(const float* __restrict__ w1,
                                                    const float* __restrict__ w2,
                                                    int n4, unsigned* out) {
  const float4* w4 = (const float4*)(blockIdx.y ? w2 : w1);
  float m = 0.f;
  for (int i = blockIdx.x * blockDim.x + threadIdx.x; i < n4;
       i += gridDim.x * blockDim.x) {
    float4 v = w4[i];
    m = fmaxf(m, fmaxf(fmaxf(fabsf(v.x), fabsf(v.y)),
                       fmaxf(fabsf(v.z), fabsf(v.w))));
  }
  m = wave_max64(m);
  __shared__ float red[4];
  const int lane = threadIdx.x & 63, wv = threadIdx.x >> 6;
  if (lane == 0) red[wv] = m;
  __syncthreads();
  if (threadIdx.x == 0) {
    float mm = fmaxf(fmaxf(red[0], red[1]), fmaxf(red[2], red[3]));
    atomicMax(out + blockIdx.y, __float_as_uint(mm));
  }
}

// ---------- per-tensor weight quantize (both tensors) ----------
__global__ __launch_bounds__(256) void wquant2_kernel(const float* __restrict__ w1,
                                                      const float* __restrict__ w2,
                                                      int n4,
                                                      const unsigned* __restrict__ amaxbits,
                                                      signed char* __restrict__ q1,
                                                      signed char* __restrict__ q2) {
  const float4* w4 = (const float4*)(blockIdx.y ? w2 : w1);
  char4* q4 = (char4*)(blockIdx.y ? q2 : q1);
  const float s = fmaxf(__uint_as_float(amaxbits[blockIdx.y]), MINR) / QPF;
  const float rs = 1.0f / s;
  for (int i = blockIdx.x * blockDim.x + threadIdx.x; i < n4;
       i += gridDim.x * blockDim.x) {
    float4 v = w4[i];
    char4 c;
    c.x = (signed char)(int)rintf(v.x * rs);
    c.y = (signed char)(int)rintf(v.y * rs);
    c.z = (signed char)(int)rintf(v.z * rs);
    c.w = (signed char)(int)rintf(v.w * rs);
    q4[i] = c;
  }
}

// ---------- per-token activation quantize (one WAVE per token) ----------
__global__ __launch_bounds__(64) void xquant_kernel(const float* __restrict__ x,
                                                    signed char* __restrict__ qx,
                                                    float* __restrict__ sx, int K) {
  const int token = blockIdx.x;
  const float4* xr = (const float4*)(x + (size_t)token * K);
  const int k4 = K >> 2;
  const int lane = threadIdx.x;
  float m = 0.f;
  for (int i = lane; i < k4; i += 64) {
    float4 v = xr[i];
    m = fmaxf(m, fmaxf(fmaxf(fabsf(v.x), fabsf(v.y)),
                       fmaxf(fabsf(v.z), fabsf(v.w))));
  }
  m = wave_max64(m);
  const float s = fmaxf(m, MINR) / QPF;
  const float rs = 1.0f / s;
  if (lane == 0) sx[token] = s;
  char4* qr = (char4*)(qx + (size_t)token * K);
  for (int i = lane; i < k4; i += 64) {
    float4 v = xr[i];   // L1-hot re-read
    char4 c;
    c.x = (signed char)(int)rintf(v.x * rs);
    c.y = (signed char)(int)rintf(v.y * rs);
    c.z = (signed char)(int)rintf(v.z * rs);
    c.w = (signed char)(int)rintf(v.w * rs);
    qr[i] = c;
  }
}

// ---------- per-token h quantize (one WAVE per token; f16 h) ----------
__global__ __launch_bounds__(64) void hquant_kernel(const _Float16* __restrict__ h,
                                                    const unsigned* __restrict__ amaxbits,
                                                    signed char* __restrict__ qh,
                                                    float* __restrict__ sh, int K) {
  const int token = blockIdx.x;
  const float s = fmaxf(__uint_as_float(amaxbits[token]), MINR) / QPF;
  const float rs = 1.0f / s;
  if (threadIdx.x == 0) sh[token] = s;
  const h8* hr = (const h8*)(h + (size_t)token * K);
  c8* qr = (c8*)(qh + (size_t)token * K);
  for (int i = threadIdx.x; i < (K >> 3); i += 64) {
    h8 v = hr[i];
    c8 c;
#pragma unroll
    for (int j = 0; j < 8; j++)
      c[j] = (signed char)(int)rintf((float)v[j] * rs);
    qr[i] = c;
  }
}

// ---------- i8 GEMM: out[n][m] = (sum_k A[n][k]*B[m][k] + bias[m]) * (sA[n]*sB) ----------
// 128x128 tile, BK=64, 4 waves 2x2, 4x4 mfma_i32_16x16x64_i8 per wave.
// XOR-swizzled LDS (conflict-free, verified R2).
// 3-buffer prefetch-distance-2 pipeline with MANUAL s_waitcnt vmcnt(4) + raw
// s_barrier: tile kt's loads were issued 2 iterations ago, tiles kt+1/kt+2 stay
// in flight ACROSS the barrier (never vmcnt(0) — the AITER/hipBLASLt pattern).
// lgkmcnt(0) before the barrier guarantees the buffer being overwritten next is
// no longer being ds_read by any wave.
template <bool GELU_EPI>
__global__ __launch_bounds__(256, 2) void gemm_i8(
    const signed char* __restrict__ A,   // [N][K]
    const signed char* __restrict__ B,   // [Mout][K]
    const float* __restrict__ bias,      // [Mout]
    const float* __restrict__ sA,        // [N] per-token scale
    const unsigned* __restrict__ sBbits, // per-tensor amax (float bits)
    void* __restrict__ outv,             // [N][Mout] (f16 if GELU_EPI else f32)
    unsigned* __restrict__ amax_out,     // [N] per-token amax of gelu(out)
    int N, int K, int Mout) {
  __shared__ __align__(16) signed char lds[3 * 16384];  // per buf: A 8K | B 8K

  const int t = threadIdx.x;
  const int lane = t & 63;
  const int wv = t >> 6;
  const int wm = wv >> 1;
  const int wn = wv & 1;
  const int rowBlk = blockIdx.y * 128;
  const int colBlk = blockIdx.x * 128;

  int ar0 = rowBlk + wv * 16 + (lane >> 2);
  int ar1 = ar0 + 64;
  if (ar0 > N - 1) ar0 = N - 1;
  if (ar1 > N - 1) ar1 = N - 1;
  const int br0 = colBlk + wv * 16 + (lane >> 2);
  const int br1 = br0 + 64;
  const int kb = (((lane & 3) ^ ((lane >> 3) & 3)) * 16);  // swizzled source chunk

  const signed char* gA0 = A + (size_t)ar0 * K + kb;
  const signed char* gA1 = A + (size_t)ar1 * K + kb;
  const signed char* gB0 = B + (size_t)br0 * K + kb;
  const signed char* gB1 = B + (size_t)br1 * K + kb;

  const v4i vzero = {0, 0, 0, 0};
  v4i acc[4][4];
#pragma unroll
  for (int i = 0; i < 4; i++)
#pragma unroll
    for (int j = 0; j < 4; j++) acc[i][j] = vzero;

  const int swz = ((lane >> 4) ^ ((lane >> 1) & 3)) * 16;
  const int aoff = (wm * 64 + (lane & 15)) * 64 + swz;
  const int boff = (wn * 64 + (lane & 15)) * 64 + swz + 8192;

  const int T = K >> 6;

  auto issue = [&](int bufo) {
    signed char* a = lds + bufo + wv * 1024;
    gl2lds16(gA0, a);
    gl2lds16(gA1, a + 4096);
    gl2lds16(gB0, a + 8192);
    gl2lds16(gB1, a + 12288);
    gA0 += 64; gA1 += 64; gB0 += 64; gB1 += 64;
  };

  // prologue: tiles 0 and 1 into bufs 0,1  (8 loads/wave outstanding)
  issue(0);
  if (T > 1) issue(16384);

  int cur = 0;  // byte offset of tile-kt buffer
  for (int kt = 0; kt < T; ++kt) {
    asm volatile("" ::: "memory");
    if (kt < T - 1)
      __builtin_amdgcn_s_waitcnt(0x0074);  // vmcnt(4) lgkmcnt(0): tile kt landed
    else
      __builtin_amdgcn_s_waitcnt(0x0070);  // vmcnt(0) lgkmcnt(0): last tile
    __builtin_amdgcn_s_barrier();
    asm volatile("" ::: "memory");

    if (kt + 2 < T) {
      int pf = cur + 32768;
      if (pf >= 49152) pf -= 49152;        // (kt+2)%3 buffer
      issue(pf);
    }

    v4i a[4], b[4];
#pragma unroll
    for (int mi = 0; mi < 4; mi++)
      a[mi] = *(const v4i*)(lds + cur + aoff + mi * 1024);
#pragma unroll
    for (int ni = 0; ni < 4; ni++)
      b[ni] = *(const v4i*)(lds + cur + boff + ni * 1024);
#pragma unroll
    for (int mi = 0; mi < 4; mi++)
#pragma unroll
      for (int ni = 0; ni < 4; ni++)
        acc[mi][ni] = __builtin_amdgcn_mfma_i32_16x16x64_i8(a[mi], b[ni],
                                                            acc[mi][ni], 0, 0, 0);
    cur += 16384;
    if (cur >= 49152) cur = 0;
  }

  // epilogue: C/D layout col=lane&15, row=(lane>>4)*4+r
  const float sB = fmaxf(__uint_as_float(*sBbits), MINR) / QPF;
  const int colb = colBlk + wn * 64 + (lane & 15);
  const int rowb = rowBlk + wm * 64 + (lane >> 4) * 4;

  float bv[4];
#pragma unroll
  for (int ni = 0; ni < 4; ni++) bv[ni] = bias[colb + ni * 16];

#pragma unroll
  for (int mi = 0; mi < 4; mi++) {
    const int row0 = rowb + mi * 16;
    float sAv[4];
#pragma unroll
    for (int r = 0; r < 4; r++) sAv[r] = (row0 + r < N) ? sA[row0 + r] : 0.f;
    float rmax[4] = {0.f, 0.f, 0.f, 0.f};
#pragma unroll
    for (int ni = 0; ni < 4; ni++) {
#pragma unroll
      for (int r = 0; r < 4; r++) {
        float v = ((float)acc[mi][ni][r] + bv[ni]) * (sAv[r] * sB);
        if (GELU_EPI) v = gelu_exact(v);
        rmax[r] = fmaxf(rmax[r], fabsf(v));
        if (row0 + r < N) {
          const size_t idx = (size_t)(row0 + r) * Mout + colb + ni * 16;
          if (GELU_EPI)
            ((_Float16*)outv)[idx] = (_Float16)v;
          else
            ((float*)outv)[idx] = v;
        }
      }
    }
    if (GELU_EPI) {
#pragma unroll
      for (int r = 0; r < 4; r++) {
        float m = rmax[r];
        m = fmaxf(m, __shfl_xor(m, 1, 64));
        m = fmaxf(m, __shfl_xor(m, 2, 64));
        m = fmaxf(m, __shfl_xor(m, 4, 64));
        m = fmaxf(m, __shfl_xor(m, 8, 64));
        if ((lane & 15) == 0 && row0 + r < N)
          atomicMax(amax_out + row0 + r, __float_as_uint(m));
      }
    }
  }
}

extern "C" void kernel_launch(void* const* d_in, const int* in_sizes, int n_in,
                              void* d_out, int out_size, void* d_ws, size_t ws_size,
                              hipStream_t stream) {
  const float* x  = (const float*)d_in[0];
  const float* w1 = (const float*)d_in[1];
  const float* b1 = (const float*)d_in[2];
  const float* w2 = (const float*)d_in[3];
  const float* b2 = (const float*)d_in[4];

  const int H = in_sizes[2];        // 3072
  const int D = in_sizes[4];        // 768
  const int N = in_sizes[0] / D;    // 12608 tokens
  float* out = (float*)d_out;

  char* ws = (char*)d_ws;
  auto alloc = [&](size_t bytes) {
    char* p = ws;
    ws += (bytes + 255) & ~(size_t)255;
    return p;
  };
  signed char* qx  = (signed char*)alloc((size_t)N * D);
  signed char* qw1 = (signed char*)alloc((size_t)H * D);
  signed char* qw2 = (signed char*)alloc((size_t)H * D);
  signed char* qh  = (signed char*)alloc((size_t)N * H);
  float*    sx     = (float*)alloc((size_t)N * 4);
  float*    sh     = (float*)alloc((size_t)N * 4);
  unsigned* amaxh  = (unsigned*)alloc((size_t)N * 4);  // N*4 is 256-aligned here
  unsigned* wamax  = (unsigned*)alloc(256);            // adjacent to amaxh
  _Float16* h      = (_Float16*)alloc((size_t)N * H * 2);
  (void)ws_size;

  // one memset covers amaxh + wamax (adjacent allocations)
  hipMemsetAsync(amaxh, 0, (((size_t)N * 4 + 255) & ~(size_t)255) + 256, stream);

  const int n4w = (H * D) >> 2;
  amax2_kernel<<<dim3(512, 2), 256, 0, stream>>>(w1, w2, n4w, wamax);
  wquant2_kernel<<<dim3(1024, 2), 256, 0, stream>>>(w1, w2, n4w, wamax, qw1, qw2);
  xquant_kernel<<<N, 64, 0, stream>>>(x, qx, sx, D);

  dim3 g1(H / 128, (N + 127) / 128);
  gemm_i8<true><<<g1, 256, 0, stream>>>(qx, qw1, b1, sx, wamax + 0, (void*)h,
                                        amaxh, N, D, H);
  hquant_kernel<<<N, 64, 0, stream>>>(h, amaxh, qh, sh, H);

  dim3 g2(D / 128, (N + 127) / 128);
  gemm_i8<false><<<g2, 256, 0, stream>>>(qh, qw2, b2, sh, wamax + 1, (void*)out,
                                         nullptr, N, H, D);
}